// Round 1
// baseline (19339.613 us; speedup 1.0000x reference)
//
#include <hip/hip_runtime.h>
#include <hip/hip_bf16.h>
#include <hip/hip_cooperative_groups.h>

namespace cg = cooperative_groups;

#define TSTEPS 512
#define BATCH  32
#define NIN    512
#define NH     1024
#define BNH    (BATCH * NH)   // 32768

typedef __attribute__((ext_vector_type(8))) short  short8v;
typedef __attribute__((ext_vector_type(4))) float  float4v;

__device__ __forceinline__ unsigned short f2bf(float f) {
  return __builtin_bit_cast(unsigned short, __float2bfloat16(f));
}

// K-loop: z-tile (16x16) accumulation over concat(A_x | A_h) @ Wlds^T slice.
// NK = total k-iters (K/32). NX = iters taken from the "x" source.
// XF32: x source is fp32 (convert on the fly); else bf16.
template<int NK, int NX, bool XF32>
__device__ __forceinline__ float4v kloop(const float* xrow, const ushort* hxrow,
                                         const ushort* hArow, const char* smem,
                                         int bbase, int bswz, int koff) {
  constexpr int PF = 8;  // prefetch depth
  auto loadA = [&](int kk) -> short8v {
    int kg = kk * 32 + koff;
    if (kk < NX) {
      if constexpr (XF32) {
        const float* p = xrow + kg;
        float4 f0 = *(const float4*)(p);
        float4 f1 = *(const float4*)(p + 4);
        short8v r;
        r[0] = (short)f2bf(f0.x); r[1] = (short)f2bf(f0.y);
        r[2] = (short)f2bf(f0.z); r[3] = (short)f2bf(f0.w);
        r[4] = (short)f2bf(f1.x); r[5] = (short)f2bf(f1.y);
        r[6] = (short)f2bf(f1.z); r[7] = (short)f2bf(f1.w);
        return r;
      } else {
        return *(const short8v*)(hxrow + kg);
      }
    } else {
      return *(const short8v*)(hArow + (kg - NX * 32));
    }
  };
  auto loadB = [&](int kk) -> short8v {
    int byte = (bbase + (kk * 32 + koff) * 2) ^ bswz;
    return *(const short8v*)(smem + byte);
  };
  short8v abuf[PF], bbuf[PF];
#pragma unroll
  for (int i = 0; i < PF; ++i) { abuf[i] = loadA(i); bbuf[i] = loadB(i); }
  float4v acc0 = {0.f, 0.f, 0.f, 0.f}, acc1 = {0.f, 0.f, 0.f, 0.f};
#pragma unroll
  for (int kk = 0; kk < NK; ++kk) {
    short8v a = abuf[kk % PF];
    short8v b = bbuf[kk % PF];
    if (kk + PF < NK) { abuf[kk % PF] = loadA(kk + PF); bbuf[kk % PF] = loadB(kk + PF); }
    if (kk & 1) acc1 = __builtin_amdgcn_mfma_f32_16x16x32_bf16(a, b, acc1, 0, 0, 0);
    else        acc0 = __builtin_amdgcn_mfma_f32_16x16x32_bf16(a, b, acc0, 0, 0, 0);
  }
  return acc0 + acc1;
}

// Persistent cooperative kernel. 256 WGs x 256 threads, 1 WG/CU.
// WGs 0..127: layer 0 (owns h-cols [8*wg, 8*wg+8)); WGs 128..255: layer 1.
// Layer pipeline: at sync step s, layer0 computes t=s, layer1 computes t=s-1.
__global__ __launch_bounds__(256)
void lstm_persist(const float* __restrict__ x,
                  const float* __restrict__ c0_in,
                  const float* __restrict__ W0, const float* __restrict__ b0,
                  const float* __restrict__ W1, const float* __restrict__ b1,
                  ushort* __restrict__ h0buf,   // [2][BNH] bf16 ping-pong
                  ushort* __restrict__ h1buf,   // [2][BNH]
                  float* __restrict__ out) {
  extern __shared__ __align__(16) char smem[];
  float* zl = (float*)(smem + 32 * 2048 * 2);   // 32 x 33 fp32 z-tile

  const int wg    = blockIdx.x;
  const int layer = wg >> 7;
  const int j0    = (wg & 127) * 8;
  const int tid   = threadIdx.x;
  const int K     = layer ? (2 * NH) : (NIN + NH);
  const float* W    = layer ? W1 : W0;
  const float* bias = layer ? b1 : b0;

  // ---- stage W slice (32 rows x K) into LDS as bf16, XOR-swizzled ----
  {
    const int k4c = K >> 2;
    for (int idx = tid; idx < 32 * k4c; idx += 256) {
      int r  = idx / k4c;
      int k4 = (idx - r * k4c) << 2;
      int gr = (r >> 3) * NH + j0 + (r & 7);       // gate*NH + col
      float4 w = *(const float4*)(W + (size_t)gr * K + k4);
      ushort4 pk;
      pk.x = f2bf(w.x); pk.y = f2bf(w.y); pk.z = f2bf(w.z); pk.w = f2bf(w.w);
      int byte = ((r * K + k4) * 2) ^ ((r & 7) << 4);
      *(ushort4*)(smem + byte) = pk;
    }
  }

  // per-thread cell state: thread -> (batch bb, col jj)
  const int bb = tid >> 3, jj = tid & 7;
  const float bias_g0 = bias[0 * NH + j0 + jj];
  const float bias_g1 = bias[1 * NH + j0 + jj];
  const float bias_g2 = bias[2 * NH + j0 + jj];
  const float bias_g3 = bias[3 * NH + j0 + jj];
  float c = c0_in[layer * BNH + bb * NH + j0 + jj];

  // MFMA fragment geometry: wave -> (m-tile, n-tile)
  const int wv = tid >> 6, lane = tid & 63;
  const int tm = wv & 1, tn = wv >> 1;
  const int arow  = tm * 16 + (lane & 15);
  const int koff  = (lane >> 4) * 8;
  const int brow  = tn * 16 + (lane & 15);
  const int bbase = brow * K * 2;
  const int bswz  = (brow & 7) << 4;

  cg::grid_group grid = cg::this_grid();
  __syncthreads();  // W staged

  for (int s = 0; s <= TSTEPS; ++s) {
    const bool active = (layer == 0) ? (s < TSTEPS) : (s >= 1);
    const int  t      = (layer == 0) ? s : (s - 1);
    if (active) {
      float4v acc;
      if (layer == 0) {
        const float*  xr = x + ((size_t)t * BATCH + arow) * NIN;
        const ushort* hA = h0buf + ((s & 1) ^ 1) * BNH + arow * NH;
        acc = kloop<48, 16, true>(xr, nullptr, hA, smem, bbase, bswz, koff);
      } else {
        const ushort* hx = h0buf + ((s - 1) & 1) * BNH + arow * NH;
        const ushort* hA = h1buf + (s & 1) * BNH + arow * NH;
        acc = kloop<64, 32, false>(nullptr, hx, hA, smem, bbase, bswz, koff);
      }
#pragma unroll
      for (int r = 0; r < 4; ++r) {
        int m = tm * 16 + (lane >> 4) * 4 + r;   // batch row
        int n = tn * 16 + (lane & 15);           // local gate-row
        zl[m * 33 + n] = acc[r];
      }
    }
    __syncthreads();
    if (active) {
      float z0 = zl[bb * 33 + jj]      + bias_g0;
      float z1 = zl[bb * 33 + 8 + jj]  + bias_g1;
      float z2 = zl[bb * 33 + 16 + jj] + bias_g2;
      float z3 = zl[bb * 33 + 24 + jj] + bias_g3;
      float g1 = 1.f / (1.f + __expf(-z0));
      float g2 = 1.f / (1.f + __expf(-z1));
      float g3 = 1.f / (1.f + __expf(-z2));
      float o  = tanhf(z3);
      c = c * g1 + o * g2;
      float h = tanhf(c) * g3;
      unsigned short hb = f2bf(h);
      if (layer == 0) {
        h0buf[(s & 1) * BNH + bb * NH + j0 + jj] = hb;
      } else {
        h1buf[((s - 1) & 1) * BNH + bb * NH + j0 + jj] = hb;
        out[(size_t)t * BNH + bb * NH + j0 + jj] = h;
      }
    }
    grid.sync();
  }
}

// init h ping-pong buffers + copy the (h0,c0) passthrough tail of the output
__global__ void prep(const float* __restrict__ h0_in, const float* __restrict__ c0_in,
                     ushort* __restrict__ h0buf, ushort* __restrict__ h1buf,
                     float* __restrict__ out) {
  int i = blockIdx.x * blockDim.x + threadIdx.x;   // 0 .. 2*BNH-1
  if (i < BNH) {
    h0buf[BNH + i] = f2bf(h0_in[i]);               // layer0 h_{-1} -> buffer 1
    h1buf[BNH + i] = f2bf(h0_in[BNH + i]);         // layer1 h_{-1} -> buffer 1
  }
  const size_t TB = (size_t)TSTEPS * BNH;
  out[TB + i]            = h0_in[i];
  out[TB + 2 * BNH + i]  = c0_in[i];
}

extern "C" void kernel_launch(void* const* d_in, const int* in_sizes, int n_in,
                              void* d_out, int out_size, void* d_ws, size_t ws_size,
                              hipStream_t stream) {
  const float* x  = (const float*)d_in[0];
  const float* h0 = (const float*)d_in[1];
  const float* c0 = (const float*)d_in[2];
  const float* W0 = (const float*)d_in[3];
  const float* b0 = (const float*)d_in[4];
  const float* W1 = (const float*)d_in[5];
  const float* b1 = (const float*)d_in[6];
  float* out = (float*)d_out;

  ushort* h0buf = (ushort*)d_ws;          // 2*BNH bf16
  ushort* h1buf = h0buf + 2 * BNH;        // 2*BNH bf16  (total 256 KiB)

  prep<<<dim3((2 * BNH) / 256), dim3(256), 0, stream>>>(h0, c0, h0buf, h1buf, out);

  const size_t lds = 32 * 2048 * 2 + 32 * 33 * 4;  // 131072 + 4224 = 135296 B
  (void)hipFuncSetAttribute((const void*)lstm_persist,
                            hipFuncAttributeMaxDynamicSharedMemorySize, (int)lds);

  void* args[] = {(void*)&x, (void*)&c0, (void*)&W0, (void*)&b0,
                  (void*)&W1, (void*)&b1, (void*)&h0buf, (void*)&h1buf, (void*)&out};
  (void)hipLaunchCooperativeKernel((const void*)lstm_persist, dim3(256), dim3(256),
                                   args, (unsigned)lds, stream);
}

// Round 3
// 8484.416 us; speedup vs baseline: 2.2794x; 2.2794x over previous
//
#include <hip/hip_runtime.h>
#include <hip/hip_bf16.h>

#define TSTEPS 512
#define BATCH  32
#define NIN    512
#define NH     1024
#define BNH    (BATCH * NH)   // 32768

typedef __attribute__((ext_vector_type(8))) short  short8v;
typedef __attribute__((ext_vector_type(4))) float  float4v;

__device__ __forceinline__ unsigned short f2bf(float f) {
  return __builtin_bit_cast(unsigned short, __float2bfloat16(f));
}

// 16B of bf16 h-state via two 8B system-scope (LLC-coherent) loads.
// Compiler-managed: correct waitcnts, no async-asm register hazards.
__device__ __forceinline__ short8v load_h16(const ushort* p) {
  unsigned long long lo = __hip_atomic_load((const unsigned long long*)p,
                                            __ATOMIC_RELAXED, __HIP_MEMORY_SCOPE_SYSTEM);
  unsigned long long hi = __hip_atomic_load((const unsigned long long*)p + 1,
                                            __ATOMIC_RELAXED, __HIP_MEMORY_SCOPE_SYSTEM);
  union { unsigned long long u[2]; short8v v; } cv;
  cv.u[0] = lo; cv.u[1] = hi;
  return cv.v;
}

// K-loop: 16x16 z-tile over concat(src1 | src2) @ Wlds^T slice.
// XF32: src1 is fp32 x (plain cached loads + convert); else src1 = bf16 h (LLC).
// src2 always bf16 h (LLC). B from LDS, XOR-swizzled.
template<int NK, int NX, bool XF32>
__device__ __forceinline__ float4v kloop(const float* xrow, const ushort* s1row,
                                         const ushort* s2row, const char* smem,
                                         int bbase, int bswz, int koff) {
  constexpr int PF = 8;  // software prefetch depth (register rotation)
  auto loadA = [&](int kk) -> short8v {
    int kg = kk * 32 + koff;
    if (kk < NX) {
      if constexpr (XF32) {
        const float* p = xrow + kg;
        float4 f0 = *(const float4*)(p);
        float4 f1 = *(const float4*)(p + 4);
        short8v r;
        r[0] = (short)f2bf(f0.x); r[1] = (short)f2bf(f0.y);
        r[2] = (short)f2bf(f0.z); r[3] = (short)f2bf(f0.w);
        r[4] = (short)f2bf(f1.x); r[5] = (short)f2bf(f1.y);
        r[6] = (short)f2bf(f1.z); r[7] = (short)f2bf(f1.w);
        return r;
      } else {
        return load_h16(s1row + kg);
      }
    } else {
      return load_h16(s2row + (kg - NX * 32));
    }
  };
  auto loadB = [&](int kk) -> short8v {
    int byte = (bbase + (kk * 32 + koff) * 2) ^ bswz;
    return *(const short8v*)(smem + byte);
  };
  short8v abuf[PF], bbuf[PF];
#pragma unroll
  for (int i = 0; i < PF; ++i) { abuf[i] = loadA(i); bbuf[i] = loadB(i); }
  float4v acc0 = {0.f, 0.f, 0.f, 0.f}, acc1 = {0.f, 0.f, 0.f, 0.f};
#pragma unroll
  for (int kk = 0; kk < NK; ++kk) {
    short8v a = abuf[kk % PF];
    short8v b = bbuf[kk % PF];
    if (kk + PF < NK) { abuf[kk % PF] = loadA(kk + PF); bbuf[kk % PF] = loadB(kk + PF); }
    if (kk & 1) acc1 = __builtin_amdgcn_mfma_f32_16x16x32_bf16(a, b, acc1, 0, 0, 0);
    else        acc0 = __builtin_amdgcn_mfma_f32_16x16x32_bf16(a, b, acc0, 0, 0, 0);
  }
  return acc0 + acc1;
}

// Persistent kernel. 256 WGs x 256 threads, 1 WG/CU.
// WGs 0..127: layer 0 (cols [8*wg, 8*wg+8)); WGs 128..255: layer 1.
// Pipeline: at step s, layer0 computes t=s, layer1 computes t=s-1.
// Cross-step h state flows exclusively through LLC-scoped accesses, so the
// inter-step barrier needs NO cache writeback/invalidate (unlike cg grid.sync).
__global__ __launch_bounds__(256, 1)
void lstm_persist(const float* __restrict__ x,
                  const float* __restrict__ c0_in,
                  const float* __restrict__ W0, const float* __restrict__ b0,
                  const float* __restrict__ W1, const float* __restrict__ b1,
                  ushort* __restrict__ h0buf,   // [2][BNH] bf16 ping-pong (LLC)
                  ushort* __restrict__ h1buf,   // [2][BNH]
                  int* __restrict__ bar,        // group cnts @ g*32, top @512, flag @544
                  float* __restrict__ out) {
  extern __shared__ __align__(16) char smem[];
  float* zl = (float*)(smem + 32 * 2048 * 2);   // 32 x 33 fp32 z-tile

  const int wg    = blockIdx.x;
  const int layer = wg >> 7;
  const int j0    = (wg & 127) * 8;
  const int tid   = threadIdx.x;
  const int K     = layer ? (2 * NH) : (NIN + NH);
  const float* W    = layer ? W1 : W0;
  const float* bias = layer ? b1 : b0;

  // ---- stage W slice (32 rows x K) into LDS as bf16, XOR-swizzled ----
  {
    const int k4c = K >> 2;
    for (int idx = tid; idx < 32 * k4c; idx += 256) {
      int r  = idx / k4c;
      int k4 = (idx - r * k4c) << 2;
      int gr = (r >> 3) * NH + j0 + (r & 7);       // gate*NH + col
      float4 w = *(const float4*)(W + (size_t)gr * K + k4);
      ushort4 pk;
      pk.x = f2bf(w.x); pk.y = f2bf(w.y); pk.z = f2bf(w.z); pk.w = f2bf(w.w);
      int byte = ((r * K + k4) * 2) ^ ((r & 7) << 4);
      *(ushort4*)(smem + byte) = pk;
    }
  }

  // per-thread cell state: thread -> (batch bb, col jj)
  const int bb = tid >> 3, jj = tid & 7;
  const float bias_g0 = bias[0 * NH + j0 + jj];
  const float bias_g1 = bias[1 * NH + j0 + jj];
  const float bias_g2 = bias[2 * NH + j0 + jj];
  const float bias_g3 = bias[3 * NH + j0 + jj];
  float c = c0_in[layer * BNH + bb * NH + j0 + jj];

  // MFMA fragment geometry
  const int wv = tid >> 6, lane = tid & 63;
  const int tm = wv & 1, tn = wv >> 1;
  const int arow  = tm * 16 + (lane & 15);
  const int koff  = (lane >> 4) * 8;
  const int brow  = tn * 16 + (lane & 15);
  const int bbase = brow * K * 2;
  const int bswz  = (brow & 7) << 4;

  __syncthreads();  // W staged

  for (int s = 0; s <= TSTEPS; ++s) {
    const bool active = (layer == 0) ? (s < TSTEPS) : (s >= 1);
    const int  t      = (layer == 0) ? s : (s - 1);
    if (active) {
      float4v acc;
      if (layer == 0) {
        const float*  xr = x + ((size_t)t * BATCH + arow) * NIN;
        const ushort* hA = h0buf + ((s & 1) ^ 1) * BNH + arow * NH;
        acc = kloop<48, 16, true>(xr, nullptr, hA, smem, bbase, bswz, koff);
      } else {
        const ushort* hx = h0buf + ((s - 1) & 1) * BNH + arow * NH;
        const ushort* hA = h1buf + (s & 1) * BNH + arow * NH;
        acc = kloop<64, 32, false>(nullptr, hx, hA, smem, bbase, bswz, koff);
      }
#pragma unroll
      for (int r = 0; r < 4; ++r) {
        int m = tm * 16 + (lane >> 4) * 4 + r;   // batch row
        int n = tn * 16 + (lane & 15);           // local gate-row
        zl[m * 33 + n] = acc[r];
      }
    }
    __syncthreads();
    if (active) {
      float z0 = zl[bb * 33 + jj]      + bias_g0;
      float z1 = zl[bb * 33 + 8 + jj]  + bias_g1;
      float z2 = zl[bb * 33 + 16 + jj] + bias_g2;
      float z3 = zl[bb * 33 + 24 + jj] + bias_g3;
      float g1 = 1.f / (1.f + __expf(-z0));
      float g2 = 1.f / (1.f + __expf(-z1));
      float g3 = 1.f / (1.f + __expf(-z2));
      float o  = tanhf(z3);
      c = c * g1 + o * g2;
      float h = tanhf(c) * g3;
      unsigned short hb = f2bf(h);
      if (layer == 0) {
        __hip_atomic_store(&h0buf[(s & 1) * BNH + bb * NH + j0 + jj], hb,
                           __ATOMIC_RELAXED, __HIP_MEMORY_SCOPE_SYSTEM);
      } else {
        __hip_atomic_store(&h1buf[((s - 1) & 1) * BNH + bb * NH + j0 + jj], hb,
                           __ATOMIC_RELAXED, __HIP_MEMORY_SCOPE_SYSTEM);
        out[(size_t)t * BNH + bb * NH + j0 + jj] = h;
      }
    }
    // each wave drains its scoped stores (store-ack == visible at LLC),
    // then the WG arrives at the 2-level global barrier.
    asm volatile("s_waitcnt vmcnt(0)" ::: "memory");
    __syncthreads();
    if (s < TSTEPS) {
      if (tid == 0) {
        const int g = wg >> 4;   // 16 groups of 16 WGs, counters 128B apart
        int v = __hip_atomic_fetch_add(&bar[g * 32], 1,
                                       __ATOMIC_RELAXED, __HIP_MEMORY_SCOPE_SYSTEM);
        if (v == 16 * (s + 1) - 1) {
          int w = __hip_atomic_fetch_add(&bar[512], 1,
                                         __ATOMIC_RELAXED, __HIP_MEMORY_SCOPE_SYSTEM);
          if (w == 16 * (s + 1) - 1) {
            __hip_atomic_store(&bar[544], s + 1,
                               __ATOMIC_RELAXED, __HIP_MEMORY_SCOPE_SYSTEM);
          }
        }
        while (__hip_atomic_load(&bar[544], __ATOMIC_RELAXED,
                                 __HIP_MEMORY_SCOPE_SYSTEM) < s + 1)
          __builtin_amdgcn_s_sleep(1);
      }
      __syncthreads();
    }
  }
}

// init h ping-pong buffers, zero barrier, copy the (h0,c0) passthrough tail
__global__ void prep(const float* __restrict__ h0_in, const float* __restrict__ c0_in,
                     ushort* __restrict__ h0buf, ushort* __restrict__ h1buf,
                     int* __restrict__ bar, float* __restrict__ out) {
  int i = blockIdx.x * blockDim.x + threadIdx.x;   // 0 .. 2*BNH-1
  if (i < BNH) {
    __hip_atomic_store(&h0buf[BNH + i], f2bf(h0_in[i]),
                       __ATOMIC_RELAXED, __HIP_MEMORY_SCOPE_SYSTEM);
    __hip_atomic_store(&h1buf[BNH + i], f2bf(h0_in[BNH + i]),
                       __ATOMIC_RELAXED, __HIP_MEMORY_SCOPE_SYSTEM);
  }
  if (i < 576) {
    __hip_atomic_store(&bar[i], 0, __ATOMIC_RELAXED, __HIP_MEMORY_SCOPE_SYSTEM);
  }
  const size_t TB = (size_t)TSTEPS * BNH;
  out[TB + i]           = h0_in[i];
  out[TB + 2 * BNH + i] = c0_in[i];
}

extern "C" void kernel_launch(void* const* d_in, const int* in_sizes, int n_in,
                              void* d_out, int out_size, void* d_ws, size_t ws_size,
                              hipStream_t stream) {
  const float* x  = (const float*)d_in[0];
  const float* h0 = (const float*)d_in[1];
  const float* c0 = (const float*)d_in[2];
  const float* W0 = (const float*)d_in[3];
  const float* b0 = (const float*)d_in[4];
  const float* W1 = (const float*)d_in[5];
  const float* b1 = (const float*)d_in[6];
  float* out = (float*)d_out;

  ushort* h0buf = (ushort*)d_ws;          // 2*BNH bf16
  ushort* h1buf = h0buf + 2 * BNH;        // 2*BNH bf16  (256 KiB total)
  int*    bar   = (int*)((char*)d_ws + 262144);

  prep<<<dim3((2 * BNH) / 256), dim3(256), 0, stream>>>(h0, c0, h0buf, h1buf, bar, out);

  const size_t lds = 32 * 2048 * 2 + 32 * 33 * 4;  // 135296 B
  (void)hipFuncSetAttribute((const void*)lstm_persist,
                            hipFuncAttributeMaxDynamicSharedMemorySize, (int)lds);

  void* args[] = {(void*)&x, (void*)&c0, (void*)&W0, (void*)&b0,
                  (void*)&W1, (void*)&b1, (void*)&h0buf, (void*)&h1buf,
                  (void*)&bar, (void*)&out};
  (void)hipLaunchCooperativeKernel((const void*)lstm_persist, dim3(256), dim3(256),
                                   args, (unsigned)lds, stream);
}

// Round 4
// 5967.222 us; speedup vs baseline: 3.2410x; 1.4218x over previous
//
#include <hip/hip_runtime.h>
#include <hip/hip_bf16.h>

#define TSTEPS 512
#define BATCH  32
#define NIN    512
#define NH     1024
#define BNH    (BATCH * NH)   // 32768

typedef __attribute__((ext_vector_type(8))) short  short8v;
typedef __attribute__((ext_vector_type(4))) float  float4v;

__device__ __forceinline__ unsigned short f2bf(float f) {
  return __builtin_bit_cast(unsigned short, __float2bfloat16(f));
}

// K-loop: 16x16 z-tile over concat(src1 | src2) @ Wlds^T slice.
// All A-side loads are NORMAL cached loads (L1/L2). Coherence is handled by
// the per-step acquire fence (buffer_inv) before this runs.
// XF32: src1 is fp32 x (convert on the fly); else src1 is bf16 h.
template<int NK, int NX, bool XF32>
__device__ __forceinline__ float4v kloop(const float* xrow, const ushort* s1row,
                                         const ushort* s2row, const char* smem,
                                         int bbase, int bswz, int koff) {
  constexpr int PF = 8;  // software prefetch depth (register rotation)
  auto loadA = [&](int kk) -> short8v {
    int kg = kk * 32 + koff;
    if (kk < NX) {
      if constexpr (XF32) {
        const float* p = xrow + kg;
        float4 f0 = *(const float4*)(p);
        float4 f1 = *(const float4*)(p + 4);
        short8v r;
        r[0] = (short)f2bf(f0.x); r[1] = (short)f2bf(f0.y);
        r[2] = (short)f2bf(f0.z); r[3] = (short)f2bf(f0.w);
        r[4] = (short)f2bf(f1.x); r[5] = (short)f2bf(f1.y);
        r[6] = (short)f2bf(f1.z); r[7] = (short)f2bf(f1.w);
        return r;
      } else {
        return *(const short8v*)(s1row + kg);
      }
    } else {
      return *(const short8v*)(s2row + (kg - NX * 32));
    }
  };
  auto loadB = [&](int kk) -> short8v {
    int byte = (bbase + (kk * 32 + koff) * 2) ^ bswz;
    return *(const short8v*)(smem + byte);
  };
  short8v abuf[PF], bbuf[PF];
#pragma unroll
  for (int i = 0; i < PF; ++i) { abuf[i] = loadA(i); bbuf[i] = loadB(i); }
  float4v acc0 = {0.f, 0.f, 0.f, 0.f}, acc1 = {0.f, 0.f, 0.f, 0.f};
#pragma unroll
  for (int kk = 0; kk < NK; ++kk) {
    short8v a = abuf[kk % PF];
    short8v b = bbuf[kk % PF];
    if (kk + PF < NK) { abuf[kk % PF] = loadA(kk + PF); bbuf[kk % PF] = loadB(kk + PF); }
    if (kk & 1) acc1 = __builtin_amdgcn_mfma_f32_16x16x32_bf16(a, b, acc1, 0, 0, 0);
    else        acc0 = __builtin_amdgcn_mfma_f32_16x16x32_bf16(a, b, acc0, 0, 0, 0);
  }
  return acc0 + acc1;
}

// Persistent kernel, 256 WGs x 256 threads, 1 WG/CU (LDS-bound).
// Layer = XCD-residue grouping: (wg&7)<4 -> layer0 (XCDs 0-3), else layer1.
// Each layer: independent 512-step loop, own 128-WG two-level barrier and
// monotone step counter. h0 flows layer0->-{layer0,layer1} via a depth-4 ring;
// h1 flows layer1->layer1 via a depth-2 ring.
//   layer0 step s needs: cnt0 >= s   (own prev)   and cnt1 >= s-3 (ring reuse)
//   layer1 step t needs: cnt1 >= t   (own prev)   and cnt0 >= t+1 (h0_t ready)
// Producers store h/out write-through (sc0 sc1 -> LLC, L2 never dirty);
// consumers run buffer_inv (acquire-agent fence) after the poll, then use
// plain cached loads. No wbl2, no grid-wide barrier.
__global__ __launch_bounds__(256, 1)
void lstm_persist(const float* __restrict__ x,
                  const float* __restrict__ c0_in,
                  const float* __restrict__ W0, const float* __restrict__ b0,
                  const float* __restrict__ W1, const float* __restrict__ b1,
                  ushort* __restrict__ ring0,   // [4][BNH] bf16
                  ushort* __restrict__ ring1,   // [2][BNH] bf16
                  int* __restrict__ bar,        // grp@(0..15)*32, top@512+L*32, cnt@576+L*32
                  float* __restrict__ out) {
  extern __shared__ __align__(16) char smem[];
  float* zl = (float*)(smem + 32 * 2048 * 2);   // 32 x 33 fp32 z-tile

  const int wg    = blockIdx.x;
  const int tid   = threadIdx.x;
  const int res   = wg & 7;
  const int layer = res >> 2;                   // XCDs 0-3 -> layer0, 4-7 -> layer1
  const int rank  = (wg >> 3) * 4 + (res & 3);  // 0..127 within layer
  const int j0    = rank * 8;
  const int grp   = layer * 8 + (rank >> 4);    // 16 groups of 16 WGs
  const int K     = layer ? (2 * NH) : (NIN + NH);
  const float* W    = layer ? W1 : W0;
  const float* bias = layer ? b1 : b0;

  // ---- stage W slice (32 rows x K) into LDS as bf16, XOR-swizzled ----
  {
    const int k4c = K >> 2;
    for (int idx = tid; idx < 32 * k4c; idx += 256) {
      int r  = idx / k4c;
      int k4 = (idx - r * k4c) << 2;
      int gr = (r >> 3) * NH + j0 + (r & 7);       // gate*NH + col
      float4 w = *(const float4*)(W + (size_t)gr * K + k4);
      ushort4 pk;
      pk.x = f2bf(w.x); pk.y = f2bf(w.y); pk.z = f2bf(w.z); pk.w = f2bf(w.w);
      int byte = ((r * K + k4) * 2) ^ ((r & 7) << 4);
      *(ushort4*)(smem + byte) = pk;
    }
  }

  // per-thread cell state: thread -> (batch bb, col jj)
  const int bb = tid >> 3, jj = tid & 7;
  const float bias_g0 = bias[0 * NH + j0 + jj];
  const float bias_g1 = bias[1 * NH + j0 + jj];
  const float bias_g2 = bias[2 * NH + j0 + jj];
  const float bias_g3 = bias[3 * NH + j0 + jj];
  float c = c0_in[layer * BNH + bb * NH + j0 + jj];

  // MFMA fragment geometry
  const int wv = tid >> 6, lane = tid & 63;
  const int tm = wv & 1, tn = wv >> 1;
  const int arow  = tm * 16 + (lane & 15);
  const int koff  = (lane >> 4) * 8;
  const int brow  = tn * 16 + (lane & 15);
  const int bbase = brow * K * 2;
  const int bswz  = (brow & 7) << 4;

  int* own_cnt = &bar[576 + layer * 32];
  int* oth_cnt = &bar[576 + (1 - layer) * 32];

  __syncthreads();  // W staged

  for (int it = 0; it < TSTEPS; ++it) {
    // ---- wait for dependencies, then invalidate stale L1/L2 ----
    if (tid == 0) {
      const int need_own = it;
      const int need_oth = layer ? (it + 1) : (it - 3);
      while (__hip_atomic_load(own_cnt, __ATOMIC_RELAXED, __HIP_MEMORY_SCOPE_SYSTEM) < need_own ||
             __hip_atomic_load(oth_cnt, __ATOMIC_RELAXED, __HIP_MEMORY_SCOPE_SYSTEM) < need_oth)
        __builtin_amdgcn_s_sleep(1);
      // acquire at agent scope: s_waitcnt + buffer_inv (L1+L2 invalidate).
      // L2 is never dirty (all shared-state stores are write-through sc0sc1).
      __builtin_amdgcn_fence(__ATOMIC_ACQUIRE, "agent");
    }
    __syncthreads();

    // ---- gate pre-activations via MFMA ----
    float4v acc;
    if (layer == 0) {
      const float*  xr = x + ((size_t)it * BATCH + arow) * NIN;
      const ushort* hA = ring0 + ((it + 3) & 3) * BNH + arow * NH;   // (it-1) mod 4
      acc = kloop<48, 16, true>(xr, nullptr, hA, smem, bbase, bswz, koff);
    } else {
      const ushort* hx = ring0 + (it & 3) * BNH + arow * NH;         // h0 at t=it
      const ushort* hA = ring1 + ((it + 1) & 1) * BNH + arow * NH;   // (it-1) mod 2
      acc = kloop<64, 32, false>(nullptr, hx, hA, smem, bbase, bswz, koff);
    }
#pragma unroll
    for (int r = 0; r < 4; ++r) {
      int m = tm * 16 + (lane >> 4) * 4 + r;   // batch row
      int n = tn * 16 + (lane & 15);           // local gate-row
      zl[m * 33 + n] = acc[r];
    }
    __syncthreads();

    // ---- gates, state update, publish h (write-through to LLC) ----
    {
      float z0 = zl[bb * 33 + jj]      + bias_g0;
      float z1 = zl[bb * 33 + 8 + jj]  + bias_g1;
      float z2 = zl[bb * 33 + 16 + jj] + bias_g2;
      float z3 = zl[bb * 33 + 24 + jj] + bias_g3;
      float g1 = 1.f / (1.f + __expf(-z0));
      float g2 = 1.f / (1.f + __expf(-z1));
      float g3 = 1.f / (1.f + __expf(-z2));
      float o  = tanhf(z3);
      c = c * g1 + o * g2;
      float h = tanhf(c) * g3;
      unsigned short hb = f2bf(h);
      if (layer == 0) {
        __hip_atomic_store(&ring0[(it & 3) * BNH + bb * NH + j0 + jj], hb,
                           __ATOMIC_RELAXED, __HIP_MEMORY_SCOPE_SYSTEM);
      } else {
        __hip_atomic_store(&ring1[(it & 1) * BNH + bb * NH + j0 + jj], hb,
                           __ATOMIC_RELAXED, __HIP_MEMORY_SCOPE_SYSTEM);
        __hip_atomic_store(&out[(size_t)it * BNH + bb * NH + j0 + jj], h,
                           __ATOMIC_RELAXED, __HIP_MEMORY_SCOPE_SYSTEM);
      }
    }
    // drain write-through stores (ack == visible at LLC), then arrive
    asm volatile("s_waitcnt vmcnt(0)" ::: "memory");
    __syncthreads();
    if (tid == 0) {
      int v = __hip_atomic_fetch_add(&bar[grp * 32], 1,
                                     __ATOMIC_RELAXED, __HIP_MEMORY_SCOPE_SYSTEM);
      if (v == 16 * (it + 1) - 1) {
        int w = __hip_atomic_fetch_add(&bar[512 + layer * 32], 1,
                                       __ATOMIC_RELAXED, __HIP_MEMORY_SCOPE_SYSTEM);
        if (w == 8 * (it + 1) - 1) {
          __hip_atomic_store(own_cnt, it + 1,
                             __ATOMIC_RELAXED, __HIP_MEMORY_SCOPE_SYSTEM);
        }
      }
    }
  }
}

// init rings, zero barrier, copy the (h0,c0) passthrough tail of the output.
// Everything write-through (sc0 sc1) so no dirty L2 lines exist anywhere.
__global__ void prep(const float* __restrict__ h0_in, const float* __restrict__ c0_in,
                     ushort* __restrict__ ring0, ushort* __restrict__ ring1,
                     int* __restrict__ bar, float* __restrict__ out) {
  int i = blockIdx.x * blockDim.x + threadIdx.x;   // 0 .. 2*BNH-1
  if (i < BNH) {
    __hip_atomic_store(&ring0[3 * BNH + i], f2bf(h0_in[i]),          // layer0 h_{-1}
                       __ATOMIC_RELAXED, __HIP_MEMORY_SCOPE_SYSTEM);
    __hip_atomic_store(&ring1[1 * BNH + i], f2bf(h0_in[BNH + i]),    // layer1 h_{-1}
                       __ATOMIC_RELAXED, __HIP_MEMORY_SCOPE_SYSTEM);
  }
  if (i < 1024) {
    __hip_atomic_store(&bar[i], 0, __ATOMIC_RELAXED, __HIP_MEMORY_SCOPE_SYSTEM);
  }
  const size_t TB = (size_t)TSTEPS * BNH;
  __hip_atomic_store(&out[TB + i], h0_in[i],
                     __ATOMIC_RELAXED, __HIP_MEMORY_SCOPE_SYSTEM);
  __hip_atomic_store(&out[TB + 2 * BNH + i], c0_in[i],
                     __ATOMIC_RELAXED, __HIP_MEMORY_SCOPE_SYSTEM);
}

extern "C" void kernel_launch(void* const* d_in, const int* in_sizes, int n_in,
                              void* d_out, int out_size, void* d_ws, size_t ws_size,
                              hipStream_t stream) {
  const float* x  = (const float*)d_in[0];
  const float* h0 = (const float*)d_in[1];
  const float* c0 = (const float*)d_in[2];
  const float* W0 = (const float*)d_in[3];
  const float* b0 = (const float*)d_in[4];
  const float* W1 = (const float*)d_in[5];
  const float* b1 = (const float*)d_in[6];
  float* out = (float*)d_out;

  ushort* ring0 = (ushort*)d_ws;                         // 4*BNH bf16 = 256 KiB
  ushort* ring1 = (ushort*)((char*)d_ws + 262144);       // 2*BNH bf16 = 128 KiB
  int*    bar   = (int*)((char*)d_ws + 458752);          // 4 KiB counters

  prep<<<dim3((2 * BNH) / 256), dim3(256), 0, stream>>>(h0, c0, ring0, ring1, bar, out);

  const size_t lds = 32 * 2048 * 2 + 32 * 33 * 4;  // 135296 B
  (void)hipFuncSetAttribute((const void*)lstm_persist,
                            hipFuncAttributeMaxDynamicSharedMemorySize, (int)lds);

  void* args[] = {(void*)&x, (void*)&c0, (void*)&W0, (void*)&b0,
                  (void*)&W1, (void*)&b1, (void*)&ring0, (void*)&ring1,
                  (void*)&bar, (void*)&out};
  (void)hipLaunchCooperativeKernel((const void*)lstm_persist, dim3(256), dim3(256),
                                   args, (unsigned)lds, stream);
}

// Round 6
// 4729.512 us; speedup vs baseline: 4.0891x; 1.2617x over previous
//
#include <hip/hip_runtime.h>
#include <hip/hip_bf16.h>

#define TSTEPS 512
#define BATCH  32
#define NIN    512
#define NH     1024
#define BNH    (BATCH * NH)   // 32768

typedef __attribute__((ext_vector_type(8))) short  short8v;
typedef __attribute__((ext_vector_type(4))) float  float4v;

__device__ __forceinline__ unsigned short f2bf(float f) {
  return __builtin_bit_cast(unsigned short, __float2bfloat16(f));
}
__device__ __forceinline__ float4v mfma16(short8v a, short8v b, float4v c) {
  return __builtin_amdgcn_mfma_f32_16x16x32_bf16(a, b, c, 0, 0, 0);
}

// 16B of bf16 h-state via two 8B LLC-scoped loads (bypass L1/L2 -> always
// coherent, R3-proven). Compiler-managed waitcnts.
__device__ __forceinline__ short8v load_h16(const ushort* p) {
  unsigned long long lo = __hip_atomic_load((const unsigned long long*)p,
                                            __ATOMIC_RELAXED, __HIP_MEMORY_SCOPE_SYSTEM);
  unsigned long long hi = __hip_atomic_load((const unsigned long long*)p + 1,
                                            __ATOMIC_RELAXED, __HIP_MEMORY_SCOPE_SYSTEM);
  union { unsigned long long u[2]; short8v v; } cv;
  cv.u[0] = lo; cv.u[1] = hi;
  return cv.v;
}

// One 16-element A-fragment. F32: plain cached fp32 loads + convert (immutable
// inputs x / none else). !F32: bf16 via LLC-scoped loads (mutable h state).
template<bool F32>
__device__ __forceinline__ short8v loadAfrag(const void* row, int e) {
  if constexpr (F32) {
    const float* p = (const float*)row + e;
    float4 f0 = *(const float4*)(p);
    float4 f1 = *(const float4*)(p + 4);
    short8v r;
    r[0] = (short)f2bf(f0.x); r[1] = (short)f2bf(f0.y);
    r[2] = (short)f2bf(f0.z); r[3] = (short)f2bf(f0.w);
    r[4] = (short)f2bf(f1.x); r[5] = (short)f2bf(f1.y);
    r[6] = (short)f2bf(f1.z); r[7] = (short)f2bf(f1.w);
    return r;
  } else {
    return load_h16((const ushort*)row + e);
  }
}

// Dual-N-tile partial K-loop (K-split across waves). Per iter: 1 shared
// A-fragment, 2 B-fragments (N-tile 0 at bbase0, N-tile 1 at +b1off), 2 MFMAs
// into parity-split accumulators. PFA-deep A prefetch, 4-deep B prefetch.
template<int NIT, bool F32, int PFA>
__device__ __forceinline__ void kpart2(const void* row, const char* smem,
                                       int bbase0, int b1off, int bswz,
                                       int koff, int kstart,
                                       float4v& c0e, float4v& c0o,
                                       float4v& c1e, float4v& c1o) {
  constexpr int PA = (NIT < PFA) ? NIT : PFA;
  constexpr int PB = (NIT < 4) ? NIT : 4;
  short8v ab[PA], b0[PB], b1[PB];
#pragma unroll
  for (int i = 0; i < PA; ++i) ab[i] = loadAfrag<F32>(row, i * 32 + koff);
#pragma unroll
  for (int i = 0; i < PB; ++i) {
    int byte = (bbase0 + ((kstart + i) * 32 + koff) * 2) ^ bswz;
    b0[i] = *(const short8v*)(smem + byte);
    b1[i] = *(const short8v*)(smem + byte + b1off);
  }
#pragma unroll
  for (int i = 0; i < NIT; ++i) {
    short8v a = ab[i % PA], v0 = b0[i % PB], v1 = b1[i % PB];
    if (i + PA < NIT) ab[i % PA] = loadAfrag<F32>(row, (i + PA) * 32 + koff);
    if (i + PB < NIT) {
      int byte = (bbase0 + ((kstart + i + PB) * 32 + koff) * 2) ^ bswz;
      b0[i % PB] = *(const short8v*)(smem + byte);
      b1[i % PB] = *(const short8v*)(smem + byte + b1off);
    }
    if (i & 1) { c0o = mfma16(a, v0, c0o); c1o = mfma16(a, v1, c1o); }
    else       { c0e = mfma16(a, v0, c0e); c1e = mfma16(a, v1, c1e); }
  }
}

__device__ __forceinline__ void pollflag(const int* f, int need) {
  if (need <= 0) return;
  while (__hip_atomic_load(f, __ATOMIC_RELAXED, __HIP_MEMORY_SCOPE_SYSTEM) < need) {}
}

// Persistent kernel, 256 WGs x 256 threads, 1 WG/CU.
// Layer by XCD residue: (wg&7)<4 -> layer0, else layer1. rank in 0..127.
// Sync: per-producer step flags (64B apart, LLC). Producer: scoped h stores,
// vmcnt(0) drain, __syncthreads, tid0 flag store (R4-proven protocol).
// Consumer: parallel flag poll (scoped loads), __syncthreads, scoped h loads.
// ring0 depth 8 (L0 lead <= 7, backpressured by L1 flags >= it-6);
// ring1 depth 2 (within-layer lockstep makes depth 2 safe).
__global__ __launch_bounds__(256, 1)
void lstm_df(const float* __restrict__ x,
             const float* __restrict__ c0_in,
             const float* __restrict__ W0, const float* __restrict__ b0_,
             const float* __restrict__ W1, const float* __restrict__ b1_,
             ushort* __restrict__ ring0,   // [8][BNH] bf16
             ushort* __restrict__ ring1,   // [2][BNH] bf16
             int* __restrict__ flags,      // [256][16]: [0..127]=L0, [128..255]=L1
             float* __restrict__ out) {
  extern __shared__ __align__(16) char smem[];
  float* zl0 = (float*)(smem + 131072);   // k-half 0 partial z, 32x33
  float* zl1 = zl0 + 32 * 33;             // k-half 1 partial z

  const int wg    = blockIdx.x;
  const int tid   = threadIdx.x;
  const int res   = wg & 7;
  const int layer = res >> 2;
  const int rank  = (wg >> 3) * 4 + (res & 3);  // 0..127 within layer
  const int j0    = rank * 8;
  const int K     = layer ? (2 * NH) : (NIN + NH);
  const float* W    = layer ? W1 : W0;
  const float* bias = layer ? b1_ : b0_;

  // ---- stage W slice (32 rows x K) into LDS as bf16, XOR-swizzled ----
  {
    const int k4c = K >> 2;
    for (int idx = tid; idx < 32 * k4c; idx += 256) {
      int r  = idx / k4c;
      int k4 = (idx - r * k4c) << 2;
      int gr = (r >> 3) * NH + j0 + (r & 7);       // gate*NH + col
      float4 w = *(const float4*)(W + (size_t)gr * K + k4);
      ushort4 pk;
      pk.x = f2bf(w.x); pk.y = f2bf(w.y); pk.z = f2bf(w.z); pk.w = f2bf(w.w);
      int byte = ((r * K + k4) * 2) ^ ((r & 7) << 4);
      *(ushort4*)(smem + byte) = pk;
    }
  }

  const int bb = tid >> 3, jj = tid & 7;
  const float bias_g0 = bias[0 * NH + j0 + jj];
  const float bias_g1 = bias[1 * NH + j0 + jj];
  const float bias_g2 = bias[2 * NH + j0 + jj];
  const float bias_g3 = bias[3 * NH + j0 + jj];
  float c = c0_in[layer * BNH + bb * NH + j0 + jj];

  // wave roles: tm = M-tile (batch half), kh = K-half. Each wave computes
  // BOTH N-tiles for its (tm,kh) -> A loaded once, no duplication.
  const int wv = tid >> 6, lane = tid & 63;
  const int tm = wv & 1, kh = wv >> 1;
  const int arow   = tm * 16 + (lane & 15);
  const int koff   = (lane >> 4) * 8;
  const int bbase0 = (lane & 15) * K * 2;        // N-tile 0 weight row
  const int b1off  = 16 * K * 2;                 // N-tile 1 offset
  const int bswz   = ((lane & 15) & 7) << 4;     // same for both tiles
  float* zlw = kh ? zl1 : zl0;

  __syncthreads();  // W staged

  for (int it = 0; it < TSTEPS; ++it) {
    float4v c0e = {0.f,0.f,0.f,0.f}, c0o = {0.f,0.f,0.f,0.f};
    float4v c1e = {0.f,0.f,0.f,0.f}, c1o = {0.f,0.f,0.f,0.f};

    if (layer == 0) {
      // kh0 waves: dependency-free x-part overlaps kh1 waves' polling
      if (kh == 0) {
        const float* xr = x + ((size_t)it * BATCH + arow) * NIN;
        kpart2<16, true, 8>(xr, smem, bbase0, b1off, bswz, koff, 0,
                            c0e, c0o, c1e, c1o);
      } else {
        int i = tid - 128;                       // 0..127
        pollflag(&flags[i * 16], it);            // own layer finished it-1
        pollflag(&flags[(128 + i) * 16], it - 6);// ring0 slot reuse backpressure
      }
      __syncthreads();
      const ushort* hb = ring0 + (size_t)(it & 7) * BNH + arow * NH;  // h0_{it-1}
      if (kh == 0)
        kpart2<8, false, 8>(hb, smem, bbase0, b1off, bswz, koff, 16,
                            c0e, c0o, c1e, c1o);
      else
        kpart2<24, false, 16>(hb + 256, smem, bbase0, b1off, bswz, koff, 24,
                              c0e, c0o, c1e, c1o);
    } else {
      if (tid < 128) pollflag(&flags[tid * 16], it + 1);  // L0 finished it
      else           pollflag(&flags[tid * 16], it);      // own finished it-1
      __syncthreads();
      if (kh == 0) {
        const ushort* h0r = ring0 + (size_t)((it + 1) & 7) * BNH + arow * NH; // h0_it
        kpart2<32, false, 16>(h0r, smem, bbase0, b1off, bswz, koff, 0,
                              c0e, c0o, c1e, c1o);
      } else {
        const ushort* h1r = ring1 + (size_t)((it + 1) & 1) * BNH + arow * NH; // h1_{it-1}
        kpart2<32, false, 16>(h1r, smem, bbase0, b1off, bswz, koff, 32,
                              c0e, c0o, c1e, c1o);
      }
    }

    float4v accT0 = c0e + c0o, accT1 = c1e + c1o;
#pragma unroll
    for (int r = 0; r < 4; ++r) {
      int m = tm * 16 + (lane >> 4) * 4 + r;     // batch row
      zlw[m * 33 + (lane & 15)]      = accT0[r]; // N-tile 0 (gate rows 0..15)
      zlw[m * 33 + 16 + (lane & 15)] = accT1[r]; // N-tile 1 (gate rows 16..31)
    }
    __syncthreads();

    {
      float z0 = zl0[bb * 33 + jj]      + zl1[bb * 33 + jj]      + bias_g0;
      float z1 = zl0[bb * 33 + 8 + jj]  + zl1[bb * 33 + 8 + jj]  + bias_g1;
      float z2 = zl0[bb * 33 + 16 + jj] + zl1[bb * 33 + 16 + jj] + bias_g2;
      float z3 = zl0[bb * 33 + 24 + jj] + zl1[bb * 33 + 24 + jj] + bias_g3;
      float g1 = 1.f / (1.f + __expf(-z0));
      float g2 = 1.f / (1.f + __expf(-z1));
      float g3 = 1.f / (1.f + __expf(-z2));
      float o  = tanhf(z3);
      c = c * g1 + o * g2;
      float h = tanhf(c) * g3;
      unsigned short hb16 = f2bf(h);
      if (layer == 0) {
        __hip_atomic_store(&ring0[(size_t)((it + 1) & 7) * BNH + bb * NH + j0 + jj],
                           hb16, __ATOMIC_RELAXED, __HIP_MEMORY_SCOPE_SYSTEM);
      } else {
        __hip_atomic_store(&ring1[(size_t)(it & 1) * BNH + bb * NH + j0 + jj],
                           hb16, __ATOMIC_RELAXED, __HIP_MEMORY_SCOPE_SYSTEM);
        out[(size_t)it * BNH + bb * NH + j0 + jj] = h;   // plain; device never reads
      }
    }
    // drain scoped stores (ack == visible at LLC), then publish step flag
    asm volatile("s_waitcnt vmcnt(0)" ::: "memory");
    __syncthreads();
    if (tid == 0) {
      __hip_atomic_store(&flags[(layer * 128 + rank) * 16], it + 1,
                         __ATOMIC_RELAXED, __HIP_MEMORY_SCOPE_SYSTEM);
    }
  }
}

// init rings + flags, copy the (h0,c0) passthrough tail of the output
__global__ void prep(const float* __restrict__ h0_in, const float* __restrict__ c0_in,
                     ushort* __restrict__ ring0, ushort* __restrict__ ring1,
                     int* __restrict__ flags, float* __restrict__ out) {
  int i = blockIdx.x * blockDim.x + threadIdx.x;   // 0 .. 2*BNH-1
  if (i < BNH) {
    __hip_atomic_store(&ring0[i], f2bf(h0_in[i]),            // slot0 = h0 layer0 init
                       __ATOMIC_RELAXED, __HIP_MEMORY_SCOPE_SYSTEM);
    __hip_atomic_store(&ring1[BNH + i], f2bf(h0_in[BNH + i]),// slot1 = h1 layer1 init
                       __ATOMIC_RELAXED, __HIP_MEMORY_SCOPE_SYSTEM);
  }
  if (i < 256 * 16) {
    __hip_atomic_store(&flags[i], 0, __ATOMIC_RELAXED, __HIP_MEMORY_SCOPE_SYSTEM);
  }
  const size_t TB = (size_t)TSTEPS * BNH;
  out[TB + i]           = h0_in[i];
  out[TB + 2 * BNH + i] = c0_in[i];
}

extern "C" void kernel_launch(void* const* d_in, const int* in_sizes, int n_in,
                              void* d_out, int out_size, void* d_ws, size_t ws_size,
                              hipStream_t stream) {
  const float* x  = (const float*)d_in[0];
  const float* h0 = (const float*)d_in[1];
  const float* c0 = (const float*)d_in[2];
  const float* W0 = (const float*)d_in[3];
  const float* b0 = (const float*)d_in[4];
  const float* W1 = (const float*)d_in[5];
  const float* b1 = (const float*)d_in[6];
  float* out = (float*)d_out;

  ushort* ring0 = (ushort*)d_ws;                       // 8*BNH bf16 = 512 KiB
  ushort* ring1 = (ushort*)((char*)d_ws + 524288);     // 2*BNH bf16 = 128 KiB
  int*    flags = (int*)((char*)d_ws + 655360);        // 16 KiB

  prep<<<dim3((2 * BNH) / 256), dim3(256), 0, stream>>>(h0, c0, ring0, ring1, flags, out);

  const size_t lds = 131072 + 2 * 32 * 33 * 4;  // 139520 B
  (void)hipFuncSetAttribute((const void*)lstm_df,
                            hipFuncAttributeMaxDynamicSharedMemorySize, (int)lds);

  void* args[] = {(void*)&x, (void*)&c0, (void*)&W0, (void*)&b0,
                  (void*)&W1, (void*)&b1, (void*)&ring0, (void*)&ring1,
                  (void*)&flags, (void*)&out};
  (void)hipLaunchCooperativeKernel((const void*)lstm_df, dim3(256), dim3(256),
                                   args, (unsigned)lds, stream);
}

// Round 7
// 2778.048 us; speedup vs baseline: 6.9616x; 1.7025x over previous
//
#include <hip/hip_runtime.h>
#include <hip/hip_bf16.h>

#define TSTEPS 512
#define BATCH  32
#define NIN    512
#define NH     1024
#define BNH    (BATCH * NH)   // 32768

typedef __attribute__((ext_vector_type(8))) short  short8v;
typedef __attribute__((ext_vector_type(4))) float  float4v;
typedef unsigned long long ull;

__device__ __forceinline__ unsigned short f2bf(float f) {
  return __builtin_bit_cast(unsigned short, __float2bfloat16(f));
}
__device__ __forceinline__ float4v mfma16(short8v a, short8v b, float4v c) {
  return __builtin_amdgcn_mfma_f32_16x16x32_bf16(a, b, c, 0, 0, 0);
}

// h state swizzle (8B-atomic-pair layout): element (b,k) lives at
//   (k>>5)*1024 + (b>>4)*512 + ((k>>2)&1)*256 + ((b&15)|(((k>>3)&3)<<4))*4 + (k&3)
// so a wave's A-fragment load (lane l, k-block kg, m-tile mt) is two 8B loads
// at  base + kg*1024 + mt*512 + l*4  and +256 elems -- 512B contiguous/wave.
__device__ __forceinline__ int swzh(int b, int k) {
  return (k >> 5) * 1024 + (b >> 4) * 512 + ((k >> 2) & 1) * 256 +
         (((b & 15) | (((k >> 3) & 3) << 4)) << 2) + (k & 3);
}
// x bf16 swizzle (plain 16B layout): lane reads 16B at kg*1024+mt*512+l*8.
__device__ __forceinline__ int swzx(int b, int k) {
  return (k >> 5) * 1024 + (b >> 4) * 512 +
         (((b & 15) | (((k >> 3) & 3) << 4)) << 3) + (k & 7);
}

// 8-k-iter partial GEMM: A from memory (X16: plain 16B bf16; else scoped 8B
// pairs via LLC), B from registers. acc[mt][nt] over 2 M-tiles x 2 N-tiles.
template<bool X16>
__device__ __forceinline__ void kpart8(const ushort* __restrict__ base, int kgb,
                                       int lane, const short8v (&wreg)[8][2],
                                       float4v (&acc)[2][2]) {
  if constexpr (X16) {
    short8v f[2][8];
#pragma unroll
    for (int mt = 0; mt < 2; ++mt)
#pragma unroll
      for (int q = 0; q < 8; ++q)
        f[mt][q] = *(const short8v*)(base + (size_t)(kgb + q) * 1024 + mt * 512 + lane * 8);
#pragma unroll
    for (int q = 0; q < 8; ++q)
#pragma unroll
      for (int mt = 0; mt < 2; ++mt) {
        acc[mt][0] = mfma16(f[mt][q], wreg[q][0], acc[mt][0]);
        acc[mt][1] = mfma16(f[mt][q], wreg[q][1], acc[mt][1]);
      }
  } else {
    ull lo[2][8], hi[2][8];
#pragma unroll
    for (int mt = 0; mt < 2; ++mt)
#pragma unroll
      for (int q = 0; q < 8; ++q) {
        const ull* p = (const ull*)(base + (size_t)(kgb + q) * 1024 + mt * 512 + lane * 4);
        lo[mt][q] = __hip_atomic_load(p,      __ATOMIC_RELAXED, __HIP_MEMORY_SCOPE_SYSTEM);
        hi[mt][q] = __hip_atomic_load(p + 64, __ATOMIC_RELAXED, __HIP_MEMORY_SCOPE_SYSTEM);
      }
#pragma unroll
    for (int q = 0; q < 8; ++q)
#pragma unroll
      for (int mt = 0; mt < 2; ++mt) {
        union { ull u[2]; short8v v; } cv;
        cv.u[0] = lo[mt][q]; cv.u[1] = hi[mt][q];
        acc[mt][0] = mfma16(cv.v, wreg[q][0], acc[mt][0]);
        acc[mt][1] = mfma16(cv.v, wreg[q][1], acc[mt][1]);
      }
  }
}

// per-wave flag poll: lanes share cnt flags (cnt = 32 or 64), spin until all
// >= need. asm memory clobber stops the compiler hoisting kpart loads above.
__device__ __forceinline__ void wave_poll(const int* __restrict__ flags,
                                          int base, int cnt, int need, int lane) {
  if (need <= 0) return;
  const int* f = flags + (size_t)(base + (lane & (cnt - 1))) * 4;
  while (!__all(__hip_atomic_load(f, __ATOMIC_RELAXED, __HIP_MEMORY_SCOPE_SYSTEM) >= need)) {}
  asm volatile("" ::: "memory");
}

// Persistent kernel: 256 WGs x 512 threads (8 waves, 2/SIMD), 1 WG/CU.
// Layer by XCD residue: (wg&7)<4 -> layer0, else layer1. rank 0..127.
// Wave roles (K-split, weights in VGPRs, B never touches LDS):
//   L0: wv0-1 x-part (plain bf16), wv2-5 h0-part (scoped), wv6-7 backpressure poll
//   L1: wv0-3 h0-part (scoped, cross-layer), wv4-7 h1-part (scoped, tight chain)
// Sync: per-producer step flags; consumer waves poll only their 32 producers.
__global__ __launch_bounds__(512, 2)
void lstm_rs(const float* __restrict__ c0_in,
             const float* __restrict__ W0, const float* __restrict__ b0_,
             const float* __restrict__ W1, const float* __restrict__ b1_,
             const ushort* __restrict__ xbf,
             ushort* __restrict__ ring0,   // [8][BNH] bf16, swizzled
             ushort* __restrict__ ring1,   // [2][BNH] bf16, swizzled
             int* __restrict__ flags,      // 256 producers, stride 4 ints
             float* __restrict__ out) {
  __shared__ float zl[8][32][33];          // per-wave z partials (33.8 KB)

  const int wg    = blockIdx.x;
  const int tid   = threadIdx.x;
  const int res   = wg & 7;
  const int layer = res >> 2;
  const int rank  = (wg >> 3) * 4 + (res & 3);
  const int j0    = rank * 8;
  const int K     = layer ? (2 * NH) : (NIN + NH);
  const float* W    = layer ? W1 : W0;
  const float* bias = layer ? b1_ : b0_;

  const int wv = tid >> 6, lane = tid & 63;
  const bool kactive = layer ? true : (wv < 6);

  // ---- preload this wave's weight K-slice into registers (once) ----
  short8v wreg[8][2];
  if (kactive) {
    const int wkbase = wv * 256;
#pragma unroll
    for (int q = 0; q < 8; ++q)
#pragma unroll
      for (int nt = 0; nt < 2; ++nt) {
        int n  = nt * 16 + (lane & 15);
        int gr = (n >> 3) * NH + j0 + (n & 7);
        int k  = wkbase + q * 32 + (lane >> 4) * 8;
        const float* p = W + (size_t)gr * K + k;
        float4 f0 = *(const float4*)p;
        float4 f1 = *(const float4*)(p + 4);
        short8v r;
        r[0] = (short)f2bf(f0.x); r[1] = (short)f2bf(f0.y);
        r[2] = (short)f2bf(f0.z); r[3] = (short)f2bf(f0.w);
        r[4] = (short)f2bf(f1.x); r[5] = (short)f2bf(f1.y);
        r[6] = (short)f2bf(f1.z); r[7] = (short)f2bf(f1.w);
        wreg[q][nt] = r;
      }
  } else {
#pragma unroll
    for (int q = 0; q < 8; ++q) { wreg[q][0] = short8v{}; wreg[q][1] = short8v{}; }
  }

  // zero my z slice (idle L0 waves 6,7 leave theirs zero forever)
  for (int i = lane; i < 32 * 33; i += 64) (&zl[wv][0][0])[i] = 0.f;

  // epilogue state (threads 0..255): thread -> (batch bb, col jj)
  const int bb = tid >> 3, jj = tid & 7;
  float c = 0.f, bg0 = 0.f, bg1 = 0.f, bg2 = 0.f, bg3 = 0.f;
  if (tid < 256) {
    bg0 = bias[0 * NH + j0 + jj];
    bg1 = bias[1 * NH + j0 + jj];
    bg2 = bias[2 * NH + j0 + jj];
    bg3 = bias[3 * NH + j0 + jj];
    c   = c0_in[layer * BNH + bb * NH + j0 + jj];
  }

  __syncthreads();

  for (int it = 0; it < TSTEPS; ++it) {
    float4v acc[2][2] = {{{0,0,0,0},{0,0,0,0}},{{0,0,0,0},{0,0,0,0}}};

    if (layer == 0) {
      if (wv < 2) {
        kpart8<true>(xbf + (size_t)it * 16384, 8 * wv, lane, wreg, acc);
      } else if (wv < 6) {
        wave_poll(flags, 32 * (wv - 2), 32, it, lane);              // own layer
        kpart8<false>(ring0 + (size_t)(it & 7) * BNH, 8 * (wv - 2), lane, wreg, acc);
      } else {
        wave_poll(flags, 128 + 64 * (wv - 6), 64, it - 6, lane);    // backpressure
      }
    } else {
      if (wv < 4) {
        wave_poll(flags, 32 * wv, 32, it + 1, lane);                // L0 done step it
        kpart8<false>(ring0 + (size_t)((it + 1) & 7) * BNH, 8 * wv, lane, wreg, acc);
      } else {
        wave_poll(flags, 128 + 32 * (wv - 4), 32, it, lane);        // own layer
        kpart8<false>(ring1 + (size_t)((it + 1) & 1) * BNH, 8 * (wv - 4), lane, wreg, acc);
      }
    }

    if (kactive) {
#pragma unroll
      for (int mt = 0; mt < 2; ++mt)
#pragma unroll
        for (int nt = 0; nt < 2; ++nt)
#pragma unroll
          for (int r = 0; r < 4; ++r)
            zl[wv][mt * 16 + (lane >> 4) * 4 + r][nt * 16 + (lane & 15)] = acc[mt][nt][r];
    }
    __syncthreads();

    if (tid < 256) {
      float zg[4];
#pragma unroll
      for (int g = 0; g < 4; ++g) {
        float s = 0.f;
#pragma unroll
        for (int w = 0; w < 8; ++w) s += zl[w][bb][g * 8 + jj];
        zg[g] = s;
      }
      float g1 = 1.f / (1.f + __expf(-(zg[0] + bg0)));
      float g2 = 1.f / (1.f + __expf(-(zg[1] + bg1)));
      float g3 = 1.f / (1.f + __expf(-(zg[2] + bg2)));
      float o  = tanhf(zg[3] + bg3);
      c = c * g1 + o * g2;
      float h = tanhf(c) * g3;
      unsigned short hb = f2bf(h);
      int so = swzh(bb, j0 + jj);
      if (layer == 0) {
        __hip_atomic_store(&ring0[(size_t)((it + 1) & 7) * BNH + so], hb,
                           __ATOMIC_RELAXED, __HIP_MEMORY_SCOPE_SYSTEM);
      } else {
        __hip_atomic_store(&ring1[(size_t)(it & 1) * BNH + so], hb,
                           __ATOMIC_RELAXED, __HIP_MEMORY_SCOPE_SYSTEM);
        out[(size_t)it * BNH + bb * NH + j0 + jj] = h;
      }
    }
    asm volatile("s_waitcnt vmcnt(0)" ::: "memory");   // drain scoped stores
    __syncthreads();
    if (tid == 0) {
      __hip_atomic_store(&flags[(size_t)(layer * 128 + rank) * 4], it + 1,
                         __ATOMIC_RELAXED, __HIP_MEMORY_SCOPE_SYSTEM);
    }
  }
}

// prep: convert x -> bf16 in fragment order, init ring slots (swizzled),
// zero flags, copy (h0,c0) passthrough tail of the output.
__global__ void prep(const float* __restrict__ x,
                     const float* __restrict__ h0_in, const float* __restrict__ c0_in,
                     ushort* __restrict__ xbf, ushort* __restrict__ ring0,
                     ushort* __restrict__ ring1, int* __restrict__ flags,
                     float* __restrict__ out) {
  int i = blockIdx.x * blockDim.x + threadIdx.x;   // 0 .. T*B*NIN-1
  {
    int t = i >> 14, rem = i & 16383;
    int b = rem >> 9, k = rem & 511;
    xbf[(size_t)t * 16384 + swzx(b, k)] = f2bf(x[i]);
  }
  if (i < BNH) {
    int b = i >> 10, j = i & 1023;
    int so = swzh(b, j);
    __hip_atomic_store(&ring0[so], f2bf(h0_in[i]),                 // h0 layer0 init, slot 0
                       __ATOMIC_RELAXED, __HIP_MEMORY_SCOPE_SYSTEM);
    __hip_atomic_store(&ring1[BNH + so], f2bf(h0_in[BNH + i]),     // h1 layer1 init, slot 1
                       __ATOMIC_RELAXED, __HIP_MEMORY_SCOPE_SYSTEM);
  }
  if (i < 1024) {
    __hip_atomic_store(&flags[i], 0, __ATOMIC_RELAXED, __HIP_MEMORY_SCOPE_SYSTEM);
  }
  if (i < 2 * BNH) {
    const size_t TB = (size_t)TSTEPS * BNH;
    out[TB + i]           = h0_in[i];
    out[TB + 2 * BNH + i] = c0_in[i];
  }
}

extern "C" void kernel_launch(void* const* d_in, const int* in_sizes, int n_in,
                              void* d_out, int out_size, void* d_ws, size_t ws_size,
                              hipStream_t stream) {
  const float* x  = (const float*)d_in[0];
  const float* h0 = (const float*)d_in[1];
  const float* c0 = (const float*)d_in[2];
  const float* W0 = (const float*)d_in[3];
  const float* b0 = (const float*)d_in[4];
  const float* W1 = (const float*)d_in[5];
  const float* b1 = (const float*)d_in[6];
  float* out = (float*)d_out;

  // ws layout (17.44 MB total; R5 proved ws >= 33.6 MB)
  ushort* xbf   = (ushort*)d_ws;                              // 16 MiB
  ushort* ring0 = (ushort*)((char*)d_ws + 16777216);          // 512 KiB
  ushort* ring1 = (ushort*)((char*)d_ws + 17301504);          // 128 KiB
  int*    flags = (int*)((char*)d_ws + 17432576);             // 4 KiB

  prep<<<dim3(32768), dim3(256), 0, stream>>>(x, h0, c0, xbf, ring0, ring1, flags, out);

  void* args[] = {(void*)&c0, (void*)&W0, (void*)&b0, (void*)&W1, (void*)&b1,
                  (void*)&xbf, (void*)&ring0, (void*)&ring1, (void*)&flags, (void*)&out};
  (void)hipLaunchCooperativeKernel((const void*)lstm_rs, dim3(256), dim3(512),
                                   args, 0, stream);
}